// Round 4
// baseline (323.243 us; speedup 1.0000x reference)
//
#include <hip/hip_runtime.h>
#include <math.h>

#define NTHR 1024
#define CAP 4096
#define BINS 4096

#define RMAX_F 0.9999999403953552f
#define RMAX_LOG_F -5.960464477539063e-08f
#define NEG_BIG -3.0e38f

__device__ __forceinline__ unsigned keyOf(float v) {
    unsigned b = __float_as_uint(v);
    return (b & 0x80000000u) ? ~b : (b | 0x80000000u);
}
__device__ __forceinline__ float valOfKey(unsigned k) {
    unsigned b = (k & 0x80000000u) ? (k ^ 0x80000000u) : ~k;
    return __uint_as_float(b);
}

// One block per row, 1024 threads.
//  P0: SAMPLED 12-bit histogram (1/8 of row, coalesced chunks) -> threshold
//      estimate with +5-sigma margin; exact-histogram FALLBACK if the verify
//      (k <= ncand <= CAP) fails.
//  P2: compaction of (key_l, ~idx), x4-unrolled loads for MLP, wave-aggregated
//      ballot atomics. Selection on raw logit keys == selection on v=l/t (t>0).
//  P3: bitonic sort desc.  P4: divide survivors once (bit-identical to ref);
//  top-k tie expansion; top-p suffix-scan cut with boundary-tie-group flags;
//  gumbel argmax; rank; serial top-K emission (v desc, idx asc); finite
//  fillers at smallest dropped indices.
__global__ __launch_bounds__(NTHR) void sampler_kernel(
    const float* __restrict__ logits,
    const float* __restrict__ temperature,
    const int* __restrict__ top_kv,
    const float* __restrict__ top_pv,
    const float* __restrict__ gumbel,
    float* __restrict__ out,
    int B, int V, int K)
{
    const int r = blockIdx.x;
    const int tid = threadIdx.x;
    const int lane = tid & 63;

    __shared__ unsigned long long cand[CAP];      // 32 KB; aliased as hist
    __shared__ int scanI[NTHR];                   // 4 KB
    __shared__ float varr[1024];
    __shared__ float Earr[1024];
    __shared__ float sfx[1024];
    __shared__ unsigned char flagArr[1024];
    __shared__ unsigned bitmap[64];
    __shared__ unsigned s_tlo;
    __shared__ int s_fallback;
    __shared__ unsigned s_prefix;
    __shared__ int s_cntgt, s_total, s_lvl;
    __shared__ int s_ncand, s_nkeep, s_rank, s_g0, s_g1;
    __shared__ unsigned long long s_amax;
    __shared__ float s_vs;

    unsigned* hist = (unsigned*)cand;             // [BINS*2], 2 privatized copies

    const float* row = logits + (long long)r * V;
    const float* urow = gumbel + (long long)r * V;

    float traw = temperature[r];
    bool greedy = traw < 1e-5f;
    float t = greedy ? 1.0f : traw;               // ref: temp<eps -> divide by 1.0
    int k = top_kv[r];
    if (k < 1) k = 1;
    if (k > V) k = V;
    float p = top_pv[r];

    const float4* row4 = (const float4*)row;
    const int V4 = V >> 2;
    const int Vt = V4 << 2;
    const unsigned cpy = tid & 1u;

    // compaction helper: collect all elements with key >= tlo into cand[]
    auto procF4 = [&](float4 l4, int i4) {
        float vv[4] = { l4.x, l4.y, l4.z, l4.w };
        #pragma unroll
        for (int j = 0; j < 4; ++j) {
            unsigned key = keyOf(vv[j]);
            bool pred = (key >= s_tlo);
            unsigned long long mask = __ballot(pred ? 1 : 0);
            if (mask) {
                int leader = __ffsll(mask) - 1;
                int cnt = __popcll(mask);
                int base = 0;
                if (lane == leader) base = atomicAdd(&s_ncand, cnt);
                base = __shfl(base, leader);
                if (pred) {
                    int pos = base + __popcll(mask & ((1ULL << lane) - 1ULL));
                    if (pos < CAP) {
                        unsigned gidx = (unsigned)(i4 * 4 + j);
                        cand[pos] = ((unsigned long long)key << 32) | (unsigned)(~gidx);
                    }
                }
            }
        }
    };
    auto compact = [&]() {
        int i = tid;
        for (; i + 3 * NTHR < V4; i += 4 * NTHR) {
            float4 a0 = row4[i];
            float4 a1 = row4[i + NTHR];
            float4 a2 = row4[i + 2 * NTHR];
            float4 a3 = row4[i + 3 * NTHR];
            procF4(a0, i); procF4(a1, i + NTHR);
            procF4(a2, i + 2 * NTHR); procF4(a3, i + 3 * NTHR);
        }
        for (; i < V4; i += NTHR) { float4 a = row4[i]; procF4(a, i); }
        for (int j = Vt + tid; j < V; j += NTHR) {
            unsigned key = keyOf(row[j]);
            bool pred = (key >= s_tlo);
            unsigned long long mask = __ballot(pred ? 1 : 0);
            if (mask) {
                int leader = __ffsll(mask) - 1;
                int cnt = __popcll(mask);
                int base = 0;
                if (lane == leader) base = atomicAdd(&s_ncand, cnt);
                base = __shfl(base, leader);
                if (pred) {
                    int pos = base + __popcll(mask & ((1ULL << lane) - 1ULL));
                    if (pos < CAP)
                        cand[pos] = ((unsigned long long)key << 32) | (unsigned)(~(unsigned)j);
                }
            }
        }
    };

    // ---------------- Phase 0: SAMPLED histogram -> threshold estimate -------
    for (int i = tid; i < BINS * 2; i += NTHR) hist[i] = 0;
    __syncthreads();
    for (int i = tid; i < V4; i += NTHR * 8) {     // ~1/8 sample, coalesced chunks
        float4 l4 = row4[i];
        atomicAdd(&hist[((keyOf(l4.x) >> 20) << 1) | cpy], 1u);
        atomicAdd(&hist[((keyOf(l4.y) >> 20) << 1) | cpy], 1u);
        atomicAdd(&hist[((keyOf(l4.z) >> 20) << 1) | cpy], 1u);
        atomicAdd(&hist[((keyOf(l4.w) >> 20) << 1) | cpy], 1u);
    }
    __syncthreads();
    {
        int base = tid << 2;
        int cs = 0;
        #pragma unroll
        for (int j = 0; j < 4; ++j)
            cs += (int)(hist[(base + j) * 2] + hist[(base + j) * 2 + 1]);
        scanI[tid] = cs;
    }
    __syncthreads();
    for (int d = 1; d < NTHR; d <<= 1) {
        int v = (tid + d < NTHR) ? scanI[tid + d] : 0;
        __syncthreads();
        scanI[tid] += v;
        __syncthreads();
    }
    const int S = scanI[0];                        // total sampled count
    long long ks = ((long long)k * S) / V;
    const int starg = (int)ks + 40 + (int)(ks >> 2);
    if (tid == 0) s_fallback = (2 * starg > S) ? 1 : 0;
    __syncthreads();
    if (!s_fallback) {
        int mine = scanI[tid];
        int above = (tid + 1 < NTHR) ? scanI[tid + 1] : 0;
        if (mine >= starg && above < starg) {       // exactly one thread
            int base = tid << 2;
            int run = above;
            for (int b = base + 3; b >= base; --b) {
                int mb = (int)(hist[b * 2] + hist[b * 2 + 1]);
                if (run + mb >= starg) { s_tlo = (unsigned)b << 20; break; }
                run += mb;
            }
        }
        __syncthreads();
        if (tid == 0) s_ncand = 0;
        __syncthreads();
        compact();                                  // overwrites hist (done with it)
        __syncthreads();
        if (tid == 0) s_fallback = (s_ncand < k || s_ncand > CAP) ? 1 : 0;
    }
    __syncthreads();

    // ---------------- FALLBACK: exact full histogram (rare) ------------------
    if (s_fallback) {
        for (int i = tid; i < BINS * 2; i += NTHR) hist[i] = 0;
        __syncthreads();
        for (int i = tid; i < V4; i += NTHR) {
            float4 l4 = row4[i];
            atomicAdd(&hist[((keyOf(l4.x) >> 20) << 1) | cpy], 1u);
            atomicAdd(&hist[((keyOf(l4.y) >> 20) << 1) | cpy], 1u);
            atomicAdd(&hist[((keyOf(l4.z) >> 20) << 1) | cpy], 1u);
            atomicAdd(&hist[((keyOf(l4.w) >> 20) << 1) | cpy], 1u);
        }
        for (int i = Vt + tid; i < V; i += NTHR)
            atomicAdd(&hist[((keyOf(row[i]) >> 20) << 1) | cpy], 1u);
        __syncthreads();
        {
            int base = tid << 2;
            int cs = 0;
            #pragma unroll
            for (int j = 0; j < 4; ++j)
                cs += (int)(hist[(base + j) * 2] + hist[(base + j) * 2 + 1]);
            scanI[tid] = cs;
        }
        __syncthreads();
        for (int d = 1; d < NTHR; d <<= 1) {
            int v = (tid + d < NTHR) ? scanI[tid + d] : 0;
            __syncthreads();
            scanI[tid] += v;
            __syncthreads();
        }
        {
            int mine = scanI[tid];
            int above = (tid + 1 < NTHR) ? scanI[tid + 1] : 0;
            if (mine >= k && above < k) {
                int base = tid << 2;
                int run = above;
                for (int b = base + 3; b >= base; --b) {
                    int mb = (int)(hist[b * 2] + hist[b * 2 + 1]);
                    if (run + mb >= k) {
                        s_prefix = (unsigned)b; s_cntgt = run;
                        s_total = run + mb; s_lvl = 0;
                        break;
                    }
                    run += mb;
                }
            }
        }
        for (int level = 1; level <= 2; ++level) {
            __syncthreads();
            if (s_total <= CAP) break;
            for (int i = tid; i < 512; i += NTHR) hist[i] = 0;
            __syncthreads();
            unsigned pfx = s_prefix;
            const int msh = 32 - (12 + 8 * (level - 1));
            const int bsh = msh - 8;
            for (int i = tid; i < V4; i += NTHR) {
                float4 l4 = row4[i];
                float vv[4] = { l4.x, l4.y, l4.z, l4.w };
                #pragma unroll
                for (int j = 0; j < 4; ++j) {
                    unsigned key = keyOf(vv[j]);
                    if ((key >> msh) == pfx)
                        atomicAdd(&hist[(((key >> bsh) & 255u) << 1) | cpy], 1u);
                }
            }
            for (int i = Vt + tid; i < V; i += NTHR) {
                unsigned key = keyOf(row[i]);
                if ((key >> msh) == pfx)
                    atomicAdd(&hist[(((key >> bsh) & 255u) << 1) | cpy], 1u);
            }
            __syncthreads();
            if (tid == 0) {
                int run = s_cntgt;
                for (int b = 255; b >= 0; --b) {
                    int mb = (int)(hist[b * 2] + hist[b * 2 + 1]);
                    if (run + mb >= k) {
                        s_prefix = (pfx << 8) | (unsigned)b;
                        s_cntgt = run; s_total = run + mb;
                        break;
                    }
                    run += mb;
                }
                s_lvl = level;
            }
        }
        __syncthreads();
        if (tid == 0) { s_tlo = s_prefix << (20 - 8 * s_lvl); s_ncand = 0; }
        __syncthreads();
        compact();
        __syncthreads();
    }

    int ncand = s_ncand; if (ncand > CAP) ncand = CAP;
    if (k > ncand) k = ncand;

    // ---------------- Phase 3: bitonic sort (descending) ----------------
    int P = 2; while (P < ncand) P <<= 1;
    for (int i = ncand + tid; i < P; i += NTHR) cand[i] = 0ULL;
    __syncthreads();
    for (int size = 2; size <= P; size <<= 1) {
        for (int stride = size >> 1; stride > 0; stride >>= 1) {
            for (int i = tid; i < P; i += NTHR) {
                int j = i ^ stride;
                if (j > i) {
                    unsigned long long a = cand[i], b = cand[j];
                    bool up = ((i & size) == 0);
                    bool sw = up ? (a < b) : (a > b);
                    if (sw) { cand[i] = b; cand[j] = a; }
                }
            }
            __syncthreads();
        }
    }

    // ---------------- Phase 4: divide once; top-k/top-p/sample ----------------
    for (int i = tid; i < 1024; i += NTHR)
        varr[i] = (i < ncand) ? (valOfKey((unsigned)(cand[i] >> 32)) / t) : NEG_BIG;
    __syncthreads();

    const float m = varr[0];
    const float tkeyV = varr[k - 1];
    int ntop = k;
    while (ntop < ncand) {
        float vi = (ntop < 1024) ? varr[ntop]
                                 : (valOfKey((unsigned)(cand[ntop] >> 32)) / t);
        if (vi != tkeyV) break;
        ++ntop;
    }
    if (ntop > 1024) ntop = 1024;

    for (int i = tid; i < 1024; i += NTHR) {
        float e = (i < ntop) ? expf(varr[i] - m) : 0.0f;
        Earr[i] = e;
        sfx[i] = e;
    }
    __syncthreads();
    for (int d = 1; d < 1024; d <<= 1) {
        float t0 = (tid + d < 1024) ? sfx[tid + d] : 0.0f;
        __syncthreads();
        sfx[tid] += t0;
        __syncthreads();
    }
    const float Zp = sfx[0];
    const float cmp = 1.0f - p;
    if (tid == 0) { s_nkeep = 0; s_rank = 0; s_amax = 0ULL; }
    for (int i = tid; i < 64; i += NTHR) bitmap[i] = 0;
    __syncthreads();
    {
        int local = 0;
        for (int i = tid; i < ntop; i += NTHR)
            if (sfx[i] / Zp > cmp) local++;
        if (local) atomicAdd(&s_nkeep, local);
    }
    __syncthreads();
    const int nkeep = s_nkeep;
    if (tid == 0) {
        float vb = varr[nkeep - 1];
        int g0 = nkeep - 1;
        while (g0 > 0 && varr[g0 - 1] == vb) --g0;
        int g1 = nkeep;
        while (g1 < ntop && varr[g1] == vb) ++g1;
        s_g0 = g0; s_g1 = g1;
    }
    __syncthreads();
    const int g0 = s_g0, g1 = s_g1;
    const int mkeep = nkeep - g0;
    for (int i = g0 + tid; i < g1; i += NTHR) {
        unsigned gi = ~(unsigned)(cand[i] & 0xFFFFFFFFull);
        int rk = 0;
        for (int j = g0; j < g1; ++j) {
            unsigned gj = ~(unsigned)(cand[j] & 0xFFFFFFFFull);
            if (gj > gi) rk++;
        }
        flagArr[i] = (rk < mkeep) ? 1 : 0;
    }
    __syncthreads();

    const float Z2 = (nkeep < 1024) ? (Zp - sfx[nkeep]) : Zp;
    const float L = logf(Z2);

    for (int i = tid; i < g1; i += NTHR) {
        if (i < g0 || flagArr[i]) {
            unsigned lo = (unsigned)(cand[i] & 0xFFFFFFFFull);
            unsigned gidx = ~lo;
            float u = urow[gidx];
            float q = -((u >= RMAX_F) ? RMAX_LOG_F : logf(u));
            float prob = Earr[i] / Z2;
            float ratio = greedy ? prob : (prob / q);
            unsigned long long comp = ((unsigned long long)__float_as_uint(ratio) << 32) | lo;
            atomicMax(&s_amax, comp);
            if (gidx < 2048) atomicOr(&bitmap[gidx >> 5], 1u << (gidx & 31));
        }
    }
    __syncthreads();
    const unsigned samp_lo = (unsigned)(s_amax & 0xFFFFFFFFull);
    const unsigned samp = ~samp_lo;
    for (int i = tid; i < ntop; i += NTHR)
        if ((unsigned)(cand[i] & 0xFFFFFFFFull) == samp_lo) s_vs = varr[i];
    __syncthreads();
    const float lp_s = (s_vs - m) - L;
    {
        int local = 0;
        for (int i = tid; i < nkeep; i += NTHR)
            if ((varr[i] - m) - L > lp_s) local++;
        if (local) atomicAdd(&s_rank, local);
    }
    __syncthreads();

    // ---------------- Phase 5: outputs ----------------
    if (tid == 0) {
        float* o_samp = out;
        float* o_idx  = out + B;
        float* o_lp   = out + B + (long long)B * (K + 1);
        float* o_rank = out + B + 2LL * B * (K + 1);
        long long rowo = (long long)r * (K + 1);

        o_samp[r] = (float)samp;
        o_idx[rowo] = (float)samp;
        o_lp[rowo] = lp_s;
        o_rank[r] = (float)s_rank;

        int ntk = (nkeep < K) ? nkeep : K;
        int slot = 0, i = 0;
        while (slot < ntk && i < g1) {
            float v = varr[i];
            int re = i + 1;
            while (re < g1 && varr[re] == v) ++re;
            long long last = -1;
            while (slot < ntk) {
                unsigned best = 0xFFFFFFFFu;
                for (int j = i; j < re; ++j) {
                    if (j >= g0 && !flagArr[j]) continue;
                    unsigned gj = ~(unsigned)(cand[j] & 0xFFFFFFFFull);
                    if ((long long)gj > last && gj < best) best = gj;
                }
                if (best == 0xFFFFFFFFu) break;
                o_idx[rowo + 1 + slot] = (float)best;
                o_lp[rowo + 1 + slot] = (v - m) - L;
                last = best; ++slot;
            }
            i = re;
        }
        if (nkeep < K) {
            int j = 0;
            for (int c = nkeep; c < K; ++c) {
                while (bitmap[j >> 5] & (1u << (j & 31))) ++j;
                o_idx[rowo + 1 + c] = (float)j;
                o_lp[rowo + 1 + c] = NEG_BIG;
                ++j;
            }
        }
    }
}

extern "C" void kernel_launch(void* const* d_in, const int* in_sizes, int n_in,
                              void* d_out, int out_size, void* d_ws, size_t ws_size,
                              hipStream_t stream) {
    const float* logits      = (const float*)d_in[0];
    const float* temperature = (const float*)d_in[1];
    const int*   top_k       = (const int*)d_in[2];
    const float* top_p       = (const float*)d_in[3];
    const float* gumbel      = (const float*)d_in[4];
    int B = in_sizes[1];
    int V = in_sizes[0] / B;
    int K = (out_size / B - 4) / 2;
    sampler_kernel<<<B, NTHR, 0, stream>>>(logits, temperature, top_k, top_p,
                                           gumbel, (float*)d_out, B, V, K);
}